// Round 2
// baseline (147.490 us; speedup 1.0000x reference)
//
#include <hip/hip_runtime.h>
#include <math.h>

#define J 25
#define NJC 75             // J * CIN
#define NWAVE 4            // waves per block
#define NTHREADS 256
#define NFPW 8             // frames per wave
#define FRSZ 1056          // bf16 per staged-X region
#define SCRW (2 * FRSZ)    // 2 regions per wave (double buffer)

// const-image layout (bf16 element offsets in CWS, per block in LDS)
#define O_A1T  0           // B for P1, natural k, 1024
#define O_APP  1024        // B for P4, k32-permuted, 1024
#define O_A4B  2048        // A for P7, k32-permuted, 1024
#define O_W2T  3072        // B for P3, k64-permuted, 2048
#define O_W3T  5120        // A for P5, k32-permuted, 2 M-tiles, 2048
#define O_W1T  7168        // A for P2, padded [tt][half][m][c8], half1=0, 1024
#define O_W4C  8192        // B for P6, k64-permuted, [c][b][j], 256
#define O_B4   8512        // 4 floats (8 bf16 slots)
#define O_BPPF 8576        // 64 fp32 bias in C-reg order [g(4)][half(2)][jj(8)]
#define CWS_SZ 8704

using bf16x2 = __attribute__((ext_vector_type(2))) __bf16;
using bf16x8 = __attribute__((ext_vector_type(8))) __bf16;
using f32x4  = __attribute__((ext_vector_type(4))) float;
using f32x16 = __attribute__((ext_vector_type(16))) float;

__device__ inline bf16x8 zero8() {
    bf16x8 z;
    #pragma unroll
    for (int j = 0; j < 8; j++) z[j] = (__bf16)0.f;
    return z;
}

#if defined(__has_builtin)
#if __has_builtin(__builtin_amdgcn_cvt_pk_bf16_f32)
#define HAVE_PK_BF16 1
#endif
#endif

__device__ inline bf16x2 cvt2(float a, float b) {
#ifdef HAVE_PK_BF16
    return __builtin_amdgcn_cvt_pk_bf16_f32(a, b);
#else
    bf16x2 r; r[0] = (__bf16)a; r[1] = (__bf16)b; return r;
#endif
}
__device__ inline bf16x8 pk8(const f32x16& acc, int st) {
    const int b = 8 * st;
    bf16x8 r;
    #pragma unroll
    for (int p = 0; p < 4; p++) {
        bf16x2 v = cvt2(acc[b + 2 * p], acc[b + 2 * p + 1]);
        r[2 * p] = v[0]; r[2 * p + 1] = v[1];
    }
    return r;
}

// ---------------------------------------------------------------------------
// Register-diet version (R2): occupancy was register-capped at ~2 waves/SIMD
// (20 weight frags = 80 VGPR + bias 32 + Z 16 + temps ~50 + addr ~15 ≈ 190).
// Changes vs R1:
//   * no A/B ILP (proven null), single-frame loop, 2 staging regions
//   * W2/W3 frags stay in LDS, re-read per frame (8 ds_read_b128/frame,
//     ~96 CU-cyc — hidden under the 640-cyc MFMA shadow); saves 32 regs
//   * P5 bias folded into MFMA C-operand (rB16[2] in C layout); deletes
//     32 v_add per frame
//   * __launch_bounds__(256,3): target 3 waves/SIMD
// ---------------------------------------------------------------------------
__global__ __launch_bounds__(NTHREADS, 3) void gcn_fused(
    const float* __restrict__ x,
    const float* __restrict__ A1, const float* __restrict__ W1, const float* __restrict__ b1,
    const float* __restrict__ A2, const float* __restrict__ W2, const float* __restrict__ b2,
    const float* __restrict__ A3, const float* __restrict__ W3, const float* __restrict__ b3,
    const float* __restrict__ A4, const float* __restrict__ W4, const float* __restrict__ b4,
    float* __restrict__ out)
{
    __shared__ __align__(16) __bf16 SCR[NWAVE * SCRW];   // 16896 B
    __shared__ __align__(16) __bf16 CWS[CWS_SZ];         // 17408 B

    const int t = threadIdx.x;

    // ================= per-block prologue: const image into CWS ===========
    {
        float* T   = (float*)SCR;       // 3189 floats, overlays X staging
        float* bpp = T + 3125;
        float* T0 = T;        float* T1 = T + 625;  float* T2 = T + 1250;
        float* T3 = T + 1875; float* T4 = T + 2500;

        if (t < 100) {
            const int m = t / J, i = t % J;
            const float* Asrc = (m == 0) ? A1 : (m == 1) ? A2 : (m == 2) ? A3 : A4;
            float row[J];
            float mx = -1e30f;
            #pragma unroll
            for (int j = 0; j < J; j++) { row[j] = Asrc[i * J + j]; mx = fmaxf(mx, row[j]); }
            float s = 0.f;
            #pragma unroll
            for (int j = 0; j < J; j++) { row[j] = __expf(row[j] - mx); s += row[j]; }
            const float inv = 1.f / s;
            float* dst = T + m * 625 + i * J;
            #pragma unroll
            for (int j = 0; j < J; j++) dst[j] = row[j] * inv;
        }
        if (t < 64) {                                      // bpp = W3^T b2 + b3
            float s = b3[t];
            #pragma unroll
            for (int l = 0; l < 32; l++) s += W3[l * 64 + t] * b2[l];
            bpp[t] = s;
        }
        __syncthreads();

        for (int idx = t; idx < 625; idx += 256) {        // App = A3s @ A2s
            const int i = idx / J, jj = idx % J;
            float s = 0.f;
            #pragma unroll
            for (int k = 0; k < J; k++) s += T2[i * J + k] * T1[k * J + jj];
            T4[idx] = s;
        }
        __syncthreads();

        // ---- A1T (natural k) | App, A4b (k32-permuted) ----
        for (int i = t; i < 1024; i += 256) {
            const int b = i >> 8, n = (i >> 3) & 31, jj = i & 7;
            const int kn = 8 * b + jj;
            CWS[O_A1T + i] = (__bf16)((kn < J && n < J) ? T0[n * J + kn] : 0.f);
            const int s = b >> 1, h = b & 1, r = 8 * s + jj;
            const int k32 = (r & 3) + 8 * (r >> 2) + 4 * h;
            CWS[O_APP + i] = (__bf16)((k32 < J && n < J) ? T4[n * J + k32] : 0.f);
            CWS[O_A4B + i] = (__bf16)((k32 < J && n < J) ? T3[n * J + k32] : 0.f);
        }
        // ---- W2T (k64-perm) | W3T (k32-perm, 2 tiles) ----
        for (int i = t; i < 2048; i += 256) {
            {
                const int b = i >> 8, n = (i >> 3) & 31, jj = i & 7;
                const int s = b >> 1, h = b & 1, r = 8 * (s & 1) + jj;
                const int d = 32 * (s >> 1) + (r & 3) + 8 * (r >> 2) + 4 * h;
                CWS[O_W2T + i] = (__bf16)W2[d * 32 + n];
            }
            {
                const int tt = i >> 10, rr = i & 1023;
                const int b = rr >> 8, m = (rr >> 3) & 31, jj = rr & 7;
                const int s = b >> 1, h = b & 1, r = 8 * s + jj;
                const int l = (r & 3) + 8 * (r >> 2) + 4 * h;
                CWS[O_W3T + i] = (__bf16)W3[l * 64 + tt * 32 + m];
            }
        }
        // ---- W1T (padded, half1=0, b1 in c=3) ----
        for (int i = t; i < 1024; i += 256) {
            const int tt = i >> 9, rq = i & 511, hf = rq >> 8, q = rq & 255;
            const int m = q >> 3, c = q & 7, d = tt * 32 + m;
            float v = 0.f;
            if (hf == 0) {
                if (c < 3) v = W1[c * 64 + d];
                else if (c == 3) v = b1[d];
            }
            CWS[O_W1T + i] = (__bf16)v;
        }
        // ---- W4c (k64-perm): [c][b][j] = W4[d64][c] ----
        {
            const int c = t >> 6, b = (t >> 3) & 7, jj = t & 7;
            const int s = b >> 1, h = b & 1, r = 8 * (s & 1) + jj;
            const int d = 32 * (s >> 1) + (r & 3) + 8 * (r >> 2) + 4 * h;
            CWS[O_W4C + t] = (c < 3) ? (__bf16)W4[d * 3 + c] : (__bf16)0.f;
        }
        // ---- fp32 bias tables ----
        {
            float* fwB = (float*)(CWS + O_BPPF);
            if (t < 64) {
                const int g = t >> 4, h = (t >> 3) & 1, jj = t & 7;
                const int tt = g >> 1, st = g & 1;
                const int row32 = (jj & 3) + 16 * st + 8 * (jj >> 2) + 4 * h;
                fwB[t] = bpp[tt * 32 + row32];
            }
            float* fb4 = (float*)(CWS + O_B4);
            if (t >= 64 && t < 68) fb4[t - 64] = (t < 67) ? b4[t - 64] : 0.f;
        }
        __syncthreads();   // CWS final; SCR free for X staging
    }

    // ================= main fused pipeline ================================
    const int w = t >> 6, lane = t & 63, ln = lane & 31, half = lane >> 5;
    const int fo = ln * 8;
    __bf16* scr = &SCR[w * SCRW];       // two 1056-el X regions

    const long fbase = ((long)blockIdx.x * NWAVE + w) * NFPW;

    // ---- one-time X-region constants in BOTH regions
    #pragma unroll
    for (int r = 0; r < 2; r++) {
        __bf16* s = scr + r * FRSZ;
        if (half == 0) s[(ln >> 3) * 264 + 24 + (ln & 7)] = (ln < J) ? (__bf16)1.f : (__bf16)0.f;
        if (lane < 21) s[3 * 264 + (lane / 7) * 8 + 1 + (lane % 7)] = (__bf16)0.f;
    }

    // X scatter coords: element i -> A[c=i%3][k=i/3]
    const int c0 = lane % 3, j0 = lane / 3;
    const int sx0 = (j0 >> 3) * 264 + c0 * 8 + (j0 & 7);
    const int i1 = 64 + lane, c1 = i1 % 3, j1 = i1 / 3;
    const int sx1 = (j1 >> 3) * 264 + c1 * 8 + (j1 & 7);

    // ---- prologue: stage frame 0 into region 0; load frame 1 into regs
    {
        const long xb = fbase * NJC;
        float v0 = x[xb + lane];
        float v1 = (lane < NJC - 64) ? x[xb + 64 + lane] : 0.f;
        scr[sx0] = (__bf16)v0;
        if (lane < NJC - 64) scr[sx1] = (__bf16)v1;
    }
    float xv0 = 0.f, xv1 = 0.f;
    if (NFPW > 1) {
        const long xb = (fbase + 1) * NJC;
        xv0 = x[xb + lane];
        if (lane < NJC - 64) xv1 = x[xb + 64 + lane];
    }

    // ---- persistent register frags (W2/W3 intentionally left in LDS)
    bf16x8 rA1T[2], rApp[2], rA4b[2], rW1[2], rW4[4];
    #pragma unroll
    for (int ks = 0; ks < 2; ks++) {
        rA1T[ks] = *(const bf16x8*)&CWS[O_A1T + (2 * ks + half) * 256 + fo];
        rApp[ks] = *(const bf16x8*)&CWS[O_APP + (2 * ks + half) * 256 + fo];
        rA4b[ks] = *(const bf16x8*)&CWS[O_A4B + (2 * ks + half) * 256 + fo];
        rW1[ks]  = *(const bf16x8*)&CWS[O_W1T + ks * 512 + half * 256 + fo];
    }
    #pragma unroll
    for (int ks = 0; ks < 4; ks++) {
        rW4[ks] = zero8();
        if (ln < 3) rW4[ks] = *(const bf16x8*)&CWS[O_W4C + ln * 64 + (half + 2 * ks) * 8];
    }
    // P5 bias as MFMA C-operand, C layout: rB16[tt][8*st+jj] = fwB[32tt+16st+8half+jj]
    f32x16 rB16[2];
    {
        const float* fwB = (const float*)(CWS + O_BPPF);
        #pragma unroll
        for (int tt = 0; tt < 2; tt++)
            #pragma unroll
            for (int st = 0; st < 2; st++) {
                f32x4 qa = *(const f32x4*)&fwB[32 * tt + 16 * st + 8 * half + 0];
                f32x4 qb = *(const f32x4*)&fwB[32 * tt + 16 * st + 8 * half + 4];
                #pragma unroll
                for (int j = 0; j < 4; j++) {
                    rB16[tt][8 * st + j]     = qa[j];
                    rB16[tt][8 * st + 4 + j] = qb[j];
                }
            }
    }
    float b4v = 0.f;
    if (ln < 3) b4v = ((const float*)(CWS + O_B4))[ln];

    // ---- shared zero accumulator (MFMA allows D != C)
    f32x16 Z;
    #pragma unroll
    for (int z = 0; z < 16; z++) Z[z] = 0.f;

    for (int fi = 0; fi < NFPW; fi++) {
        const long f = fbase + fi;
        __bf16* sc = scr + (fi & 1) * FRSZ;

        // ---- stage frame fi+1 into ALTERNATE region (overlaps this frame)
        if (fi + 1 < NFPW) {
            __bf16* sn = scr + ((fi + 1) & 1) * FRSZ;
            sn[sx0] = (__bf16)xv0;
            if (lane < NJC - 64) sn[sx1] = (__bf16)xv1;
        }
        // ---- prefetch frame fi+2's x
        if (fi + 2 < NFPW) {
            const long nxb = (f + 2) * NJC;
            xv0 = x[nxb + lane];
            if (lane < NJC - 64) xv1 = x[nxb + 64 + lane];
        }

        // ---- P1: Y^T = Xaug^T @ A1T  (A from LDS, natural k)
        bf16x8 a0 = *(const bf16x8*)&sc[half * 264 + fo];
        bf16x8 a1 = *(const bf16x8*)&sc[(2 + half) * 264 + fo];
        f32x16 accY = __builtin_amdgcn_mfma_f32_32x32x16_bf16(a0, rA1T[0], Z, 0, 0, 0);
        accY = __builtin_amdgcn_mfma_f32_32x32x16_bf16(a1, rA1T[1], accY, 0, 0, 0);

        // ---- W2 frags from LDS (issue early; consumed at P3)
        bf16x8 w2f[4];
        #pragma unroll
        for (int s = 0; s < 4; s++)
            w2f[s] = *(const bf16x8*)&CWS[O_W2T + (half + 2 * s) * 256 + fo];

        // ---- P2: H^T = relu(W1 @ Y^T); Y in-register (half0 regs 0-3 = k 0-3)
        bf16x8 yb = zero8();
        if (half == 0) {
            bf16x2 q0 = cvt2(accY[0], accY[1]);
            bf16x2 q1 = cvt2(accY[2], accY[3]);
            yb[0] = q0[0]; yb[1] = q0[1]; yb[2] = q1[0]; yb[3] = q1[1];
        }
        bf16x8 hf[4];
        #pragma unroll
        for (int tt = 0; tt < 2; tt++) {
            f32x16 acc = __builtin_amdgcn_mfma_f32_32x32x16_bf16(rW1[tt], yb, Z, 0, 0, 0);
            #pragma unroll
            for (int z = 0; z < 16; z++) acc[z] = fmaxf(acc[z], 0.f);
            hf[2 * tt]     = pk8(acc, 0);
            hf[2 * tt + 1] = pk8(acc, 1);
        }

        // ---- P3: U = H @ W2  (K=64) -> C lane=l, rows=i
        f32x16 accU = __builtin_amdgcn_mfma_f32_32x32x16_bf16(hf[0], w2f[0], Z, 0, 0, 0);
        #pragma unroll
        for (int s = 1; s < 4; s++)
            accU = __builtin_amdgcn_mfma_f32_32x32x16_bf16(hf[s], w2f[s], accU, 0, 0, 0);
        bf16x8 uf[2] = { pk8(accU, 0), pk8(accU, 1) };

        // ---- W3 frags from LDS (issue early; consumed at P5)
        bf16x8 w3f[4];
        #pragma unroll
        for (int tt = 0; tt < 2; tt++)
            #pragma unroll
            for (int ks = 0; ks < 2; ks++)
                w3f[tt * 2 + ks] = *(const bf16x8*)&CWS[O_W3T + tt * 1024 + (half + 2 * ks) * 256 + fo];

        // ---- P4: V = App @ U -> lane=i', rows=l
        f32x16 accV = __builtin_amdgcn_mfma_f32_32x32x16_bf16(uf[0], rApp[0], Z, 0, 0, 0);
        accV = __builtin_amdgcn_mfma_f32_32x32x16_bf16(uf[1], rApp[1], accV, 0, 0, 0);
        bf16x8 vf[2] = { pk8(accV, 0), pk8(accV, 1) };

        // ---- P5: HD^T = relu(W3 @ V^T + bpp), bias pre-loaded as C-in
        bf16x8 hd[4];
        #pragma unroll
        for (int tt = 0; tt < 2; tt++) {
            f32x16 acc = __builtin_amdgcn_mfma_f32_32x32x16_bf16(w3f[tt * 2 + 0], vf[0], rB16[tt], 0, 0, 0);
            acc = __builtin_amdgcn_mfma_f32_32x32x16_bf16(w3f[tt * 2 + 1], vf[1], acc, 0, 0, 0);
            #pragma unroll
            for (int z = 0; z < 16; z++) acc[z] = fmaxf(acc[z], 0.f);
            hd[2 * tt]     = pk8(acc, 0);
            hd[2 * tt + 1] = pk8(acc, 1);
        }

        // ---- P6: P = HD @ W4  (K=64) -> C lane=c, rows=i'
        f32x16 accP = __builtin_amdgcn_mfma_f32_32x32x16_bf16(hd[0], rW4[0], Z, 0, 0, 0);
        #pragma unroll
        for (int s = 1; s < 4; s++)
            accP = __builtin_amdgcn_mfma_f32_32x32x16_bf16(hd[s], rW4[s], accP, 0, 0, 0);
        bf16x8 pf[2] = { pk8(accP, 0), pk8(accP, 1) };

        // ---- P7: out = A4 @ P + b4 -> C lane=c, rows=i''
        f32x16 accO = __builtin_amdgcn_mfma_f32_32x32x16_bf16(rA4b[0], pf[0], Z, 0, 0, 0);
        accO = __builtin_amdgcn_mfma_f32_32x32x16_bf16(rA4b[1], pf[1], accO, 0, 0, 0);
        if (ln < 3) {
            const long ob = f * NJC;
            #pragma unroll
            for (int r = 0; r < 16; r++) {
                const int row = (r & 3) + 8 * (r >> 2) + 4 * half;
                if (row < J) out[ob + row * 3 + ln] = accO[r] + b4v;
            }
        }
    }
}

// ---------------------------------------------------------------------------
extern "C" void kernel_launch(void* const* d_in, const int* in_sizes, int n_in,
                              void* d_out, int out_size, void* d_ws, size_t ws_size,
                              hipStream_t stream)
{
    const float* x  = (const float*)d_in[0];
    const float* A1 = (const float*)d_in[1];
    const float* W1 = (const float*)d_in[2];
    const float* b1 = (const float*)d_in[3];
    const float* A2 = (const float*)d_in[4];
    const float* W2 = (const float*)d_in[5];
    const float* b2 = (const float*)d_in[6];
    const float* A3 = (const float*)d_in[7];
    const float* W3 = (const float*)d_in[8];
    const float* b3 = (const float*)d_in[9];
    const float* A4 = (const float*)d_in[10];
    const float* W4 = (const float*)d_in[11];
    const float* b4 = (const float*)d_in[12];
    float* out = (float*)d_out;
    (void)d_ws; (void)ws_size;

    const int NT = in_sizes[0] / NJC;                 // 65536
    const int nblocks = NT / (NWAVE * NFPW);          // 2048

    gcn_fused<<<nblocks, NTHREADS, 0, stream>>>(
        x, A1, W1, b1, A2, W2, b2, A3, W3, b3, A4, W4, b4, out);
}

// Round 3
// 140.014 us; speedup vs baseline: 1.0534x; 1.0534x over previous
//
#include <hip/hip_runtime.h>
#include <math.h>

#define J 25
#define NJC 75             // J * CIN
#define NWAVE 4            // waves per block
#define NTHREADS 256
#define NFPW 16            // frames per wave
#define FRSZ 1056          // bf16 per staged-X region
#define SCRW (2 * FRSZ)    // 2 regions per wave (double buffer)

// const-image layout (bf16 element offsets in CWS, per block in LDS)
#define O_A1T  0           // B for P1, natural k, 1024
#define O_APP  1024        // B for P4, k32-permuted, 1024
#define O_A4B  2048        // A/B for P7, k32-permuted, 1024
#define O_W2T  3072        // B for P3, k64-permuted, 2048
#define O_W3T  5120        // A for P5, k32-permuted, 2 M-tiles, 2048
#define O_W1T  7168        // A for P2, padded [tt][half][m][c8], half1=0, 1024
#define O_W4C  8192        // B for P6, k64-permuted, [c][b][j], 256
#define O_B4   8512        // 4 floats (8 bf16 slots)
#define O_BPPF 8576        // 64 fp32 bias in C-reg order [g(4)][half(2)][jj(8)]
#define CWS_SZ 8704

using bf16x2 = __attribute__((ext_vector_type(2))) __bf16;
using bf16x8 = __attribute__((ext_vector_type(8))) __bf16;
using f32x4  = __attribute__((ext_vector_type(4))) float;
using f32x16 = __attribute__((ext_vector_type(16))) float;

__device__ inline bf16x8 zero8() {
    bf16x8 z;
    #pragma unroll
    for (int j = 0; j < 8; j++) z[j] = (__bf16)0.f;
    return z;
}

#if defined(__has_builtin)
#if __has_builtin(__builtin_amdgcn_cvt_pk_bf16_f32)
#define HAVE_PK_BF16 1
#endif
#endif

__device__ inline bf16x2 cvt2(float a, float b) {
#ifdef HAVE_PK_BF16
    return __builtin_amdgcn_cvt_pk_bf16_f32(a, b);
#else
    bf16x2 r; r[0] = (__bf16)a; r[1] = (__bf16)b; return r;
#endif
}
__device__ inline bf16x8 pk8(const f32x16& acc, int st) {
    const int b = 8 * st;
    bf16x8 r;
    #pragma unroll
    for (int p = 0; p < 4; p++) {
        bf16x2 v = cvt2(acc[b + 2 * p], acc[b + 2 * p + 1]);
        r[2 * p] = v[0]; r[2 * p + 1] = v[1];
    }
    return r;
}

// ---------------------------------------------------------------------------
// R3: issue-bound model (R1 ILP null + R2 occupancy inverse-scaling).
// Per-frame issue: MFMA 640 cyc, VALU ~970 cyc; VALU dominated by the
// scattered 16-store epilogue.  Changes vs R2:
//   * weights back in registers (R2's per-frame W2/W3 ds_reads regressed)
//   * NFPW=16, 1024 blocks (prologue amortized); __launch_bounds__(256,2)
//   * P7 operand SWAP: accO = mfma(pf, rA4b) -- identical table/count, but
//     C becomes col=lane=i'' (25 lanes), rows=c in regs 0..2 of half 0.
//     Epilogue: 16 masked stores + 16 adds + 16 row-cmps -> 3 stores + 3
//     adds + one loop-invariant lane<25 mask.
//   * all global addressing via wave-uniform scalar base pointers advanced
//     per frame (SALU), lane voffsets computed once.
//   * keep R2's bias-as-C-operand for P5 (validated).
// ---------------------------------------------------------------------------
__global__ __launch_bounds__(NTHREADS, 2) void gcn_fused(
    const float* __restrict__ x,
    const float* __restrict__ A1, const float* __restrict__ W1, const float* __restrict__ b1,
    const float* __restrict__ A2, const float* __restrict__ W2, const float* __restrict__ b2,
    const float* __restrict__ A3, const float* __restrict__ W3, const float* __restrict__ b3,
    const float* __restrict__ A4, const float* __restrict__ W4, const float* __restrict__ b4,
    float* __restrict__ out)
{
    __shared__ __align__(16) __bf16 SCR[NWAVE * SCRW];   // 16896 B
    __shared__ __align__(16) __bf16 CWS[CWS_SZ];         // 17408 B

    const int t = threadIdx.x;

    // ================= per-block prologue: const image into CWS ===========
    {
        float* T   = (float*)SCR;       // overlays X staging (reused after)
        float* bpp = T + 3125;
        float* T0 = T;        float* T1 = T + 625;  float* T2 = T + 1250;
        float* T3 = T + 1875; float* T4 = T + 2500;

        if (t < 100) {
            const int m = t / J, i = t % J;
            const float* Asrc = (m == 0) ? A1 : (m == 1) ? A2 : (m == 2) ? A3 : A4;
            float row[J];
            float mx = -1e30f;
            #pragma unroll
            for (int j = 0; j < J; j++) { row[j] = Asrc[i * J + j]; mx = fmaxf(mx, row[j]); }
            float s = 0.f;
            #pragma unroll
            for (int j = 0; j < J; j++) { row[j] = __expf(row[j] - mx); s += row[j]; }
            const float inv = 1.f / s;
            float* dst = T + m * 625 + i * J;
            #pragma unroll
            for (int j = 0; j < J; j++) dst[j] = row[j] * inv;
        }
        if (t < 64) {                                      // bpp = W3^T b2 + b3
            float s = b3[t];
            #pragma unroll
            for (int l = 0; l < 32; l++) s += W3[l * 64 + t] * b2[l];
            bpp[t] = s;
        }
        __syncthreads();

        for (int idx = t; idx < 625; idx += 256) {        // App = A3s @ A2s
            const int i = idx / J, jj = idx % J;
            float s = 0.f;
            #pragma unroll
            for (int k = 0; k < J; k++) s += T2[i * J + k] * T1[k * J + jj];
            T4[idx] = s;
        }
        __syncthreads();

        // ---- A1T (natural k) | App, A4b (k32-permuted) ----
        for (int i = t; i < 1024; i += 256) {
            const int b = i >> 8, n = (i >> 3) & 31, jj = i & 7;
            const int kn = 8 * b + jj;
            CWS[O_A1T + i] = (__bf16)((kn < J && n < J) ? T0[n * J + kn] : 0.f);
            const int s = b >> 1, h = b & 1, r = 8 * s + jj;
            const int k32 = (r & 3) + 8 * (r >> 2) + 4 * h;
            CWS[O_APP + i] = (__bf16)((k32 < J && n < J) ? T4[n * J + k32] : 0.f);
            CWS[O_A4B + i] = (__bf16)((k32 < J && n < J) ? T3[n * J + k32] : 0.f);
        }
        // ---- W2T (k64-perm) | W3T (k32-perm, 2 tiles) ----
        for (int i = t; i < 2048; i += 256) {
            {
                const int b = i >> 8, n = (i >> 3) & 31, jj = i & 7;
                const int s = b >> 1, h = b & 1, r = 8 * (s & 1) + jj;
                const int d = 32 * (s >> 1) + (r & 3) + 8 * (r >> 2) + 4 * h;
                CWS[O_W2T + i] = (__bf16)W2[d * 32 + n];
            }
            {
                const int tt = i >> 10, rr = i & 1023;
                const int b = rr >> 8, m = (rr >> 3) & 31, jj = rr & 7;
                const int s = b >> 1, h = b & 1, r = 8 * s + jj;
                const int l = (r & 3) + 8 * (r >> 2) + 4 * h;
                CWS[O_W3T + i] = (__bf16)W3[l * 64 + tt * 32 + m];
            }
        }
        // ---- W1T (padded, half1=0, b1 in c=3) ----
        for (int i = t; i < 1024; i += 256) {
            const int tt = i >> 9, rq = i & 511, hf = rq >> 8, q = rq & 255;
            const int m = q >> 3, c = q & 7, d = tt * 32 + m;
            float v = 0.f;
            if (hf == 0) {
                if (c < 3) v = W1[c * 64 + d];
                else if (c == 3) v = b1[d];
            }
            CWS[O_W1T + i] = (__bf16)v;
        }
        // ---- W4c (k64-perm): [c][b][j] = W4[d64][c] ----
        {
            const int c = t >> 6, b = (t >> 3) & 7, jj = t & 7;
            const int s = b >> 1, h = b & 1, r = 8 * (s & 1) + jj;
            const int d = 32 * (s >> 1) + (r & 3) + 8 * (r >> 2) + 4 * h;
            CWS[O_W4C + t] = (c < 3) ? (__bf16)W4[d * 3 + c] : (__bf16)0.f;
        }
        // ---- fp32 bias tables ----
        {
            float* fwB = (float*)(CWS + O_BPPF);
            if (t < 64) {
                const int g = t >> 4, h = (t >> 3) & 1, jj = t & 7;
                const int tt = g >> 1, st = g & 1;
                const int row32 = (jj & 3) + 16 * st + 8 * (jj >> 2) + 4 * h;
                fwB[t] = bpp[tt * 32 + row32];
            }
            float* fb4 = (float*)(CWS + O_B4);
            if (t >= 64 && t < 68) fb4[t - 64] = (t < 67) ? b4[t - 64] : 0.f;
        }
        __syncthreads();   // CWS final; SCR free for X staging
    }

    // ================= main fused pipeline ================================
    const int w = t >> 6, lane = t & 63, ln = lane & 31, half = lane >> 5;
    const int fo = ln * 8;
    __bf16* scr = &SCR[w * SCRW];       // two 1056-el X regions

    const long fbase = ((long)blockIdx.x * NWAVE + w) * NFPW;

    // wave-uniform scalar base pointers (advanced per frame on SALU)
    const float* xp = x + fbase * NJC;        // next frame to PREFETCH from
    float* op = out + fbase * NJC;            // this frame's output base

    // ---- one-time X-region constants in BOTH regions
    #pragma unroll
    for (int r = 0; r < 2; r++) {
        __bf16* s = scr + r * FRSZ;
        if (half == 0) s[(ln >> 3) * 264 + 24 + (ln & 7)] = (ln < J) ? (__bf16)1.f : (__bf16)0.f;
        if (lane < 21) s[3 * 264 + (lane / 7) * 8 + 1 + (lane % 7)] = (__bf16)0.f;
    }

    // X scatter coords: element i -> A[c=i%3][k=i/3]
    const int c0 = lane % 3, j0 = lane / 3;
    const int sx0 = (j0 >> 3) * 264 + c0 * 8 + (j0 & 7);
    const int i1 = 64 + lane, c1 = i1 % 3, j1 = i1 / 3;
    const int sx1 = (j1 >> 3) * 264 + c1 * 8 + (j1 & 7);
    const bool ld2 = (lane < NJC - 64);

    // ---- prologue: stage frame 0 into region 0; load frame 1 into regs
    {
        scr[sx0] = (__bf16)xp[lane];
        if (ld2) scr[sx1] = (__bf16)xp[64 + lane];
        xp += NJC;
    }
    float xv0 = 0.f, xv1 = 0.f;
    if (NFPW > 1) {
        xv0 = xp[lane];
        if (ld2) xv1 = xp[64 + lane];
        xp += NJC;
    }

    // ---- persistent register frags (all weights in regs; issue-bound, so
    //      no per-frame LDS weight reads -- R2 lesson)
    bf16x8 rA1T[2], rApp[2], rA4b[2], rW1[2], rW2[4], rW3[4], rW4[4];
    #pragma unroll
    for (int ks = 0; ks < 2; ks++) {
        rA1T[ks] = *(const bf16x8*)&CWS[O_A1T + (2 * ks + half) * 256 + fo];
        rApp[ks] = *(const bf16x8*)&CWS[O_APP + (2 * ks + half) * 256 + fo];
        rA4b[ks] = *(const bf16x8*)&CWS[O_A4B + (2 * ks + half) * 256 + fo];
        rW1[ks]  = *(const bf16x8*)&CWS[O_W1T + ks * 512 + half * 256 + fo];
    }
    #pragma unroll
    for (int ks = 0; ks < 4; ks++)
        rW2[ks] = *(const bf16x8*)&CWS[O_W2T + (half + 2 * ks) * 256 + fo];
    #pragma unroll
    for (int tt = 0; tt < 2; tt++)
        #pragma unroll
        for (int ks = 0; ks < 2; ks++)
            rW3[tt * 2 + ks] = *(const bf16x8*)&CWS[O_W3T + tt * 1024 + (half + 2 * ks) * 256 + fo];
    #pragma unroll
    for (int ks = 0; ks < 4; ks++) {
        rW4[ks] = zero8();
        if (ln < 3) rW4[ks] = *(const bf16x8*)&CWS[O_W4C + ln * 64 + (half + 2 * ks) * 8];
    }
    // P5 bias as MFMA C-operand, C layout
    f32x16 rB16[2];
    {
        const float* fwB = (const float*)(CWS + O_BPPF);
        #pragma unroll
        for (int tt = 0; tt < 2; tt++)
            #pragma unroll
            for (int st = 0; st < 2; st++) {
                f32x4 qa = *(const f32x4*)&fwB[32 * tt + 16 * st + 8 * half + 0];
                f32x4 qb = *(const f32x4*)&fwB[32 * tt + 16 * st + 8 * half + 4];
                #pragma unroll
                for (int j = 0; j < 4; j++) {
                    rB16[tt][8 * st + j]     = qa[j];
                    rB16[tt][8 * st + 4 + j] = qb[j];
                }
            }
    }
    // b4 as 3 wave-uniform floats (LDS broadcast)
    const float* fb4 = (const float*)(CWS + O_B4);
    const float b40 = fb4[0], b41 = fb4[1], b42 = fb4[2];

    // ---- shared zero accumulator (MFMA allows D != C)
    f32x16 Z;
    #pragma unroll
    for (int z = 0; z < 16; z++) Z[z] = 0.f;

    const bool do_store = (lane < J);   // loop-invariant store mask (half0 only)

    #pragma unroll
    for (int fi = 0; fi < NFPW; fi++) {
        __bf16* sc = scr + (fi & 1) * FRSZ;

        // ---- stage frame fi+1 into ALTERNATE region (overlaps this frame)
        if (fi + 1 < NFPW) {
            __bf16* sn = scr + ((fi + 1) & 1) * FRSZ;
            sn[sx0] = (__bf16)xv0;
            if (ld2) sn[sx1] = (__bf16)xv1;
        }
        // ---- prefetch frame fi+2's x (scalar base, lane voffset)
        if (fi + 2 < NFPW) {
            xv0 = xp[lane];
            if (ld2) xv1 = xp[64 + lane];
            xp += NJC;
        }

        // ---- P1: Y^T = Xaug^T @ A1T  (A from LDS, natural k)
        bf16x8 a0 = *(const bf16x8*)&sc[half * 264 + fo];
        bf16x8 a1 = *(const bf16x8*)&sc[(2 + half) * 264 + fo];
        f32x16 accY = __builtin_amdgcn_mfma_f32_32x32x16_bf16(a0, rA1T[0], Z, 0, 0, 0);
        accY = __builtin_amdgcn_mfma_f32_32x32x16_bf16(a1, rA1T[1], accY, 0, 0, 0);

        // ---- P2: H^T = relu(W1 @ Y^T); Y in-register (half0 regs 0-3 = k 0-3)
        bf16x8 yb = zero8();
        if (half == 0) {
            bf16x2 q0 = cvt2(accY[0], accY[1]);
            bf16x2 q1 = cvt2(accY[2], accY[3]);
            yb[0] = q0[0]; yb[1] = q0[1]; yb[2] = q1[0]; yb[3] = q1[1];
        }
        bf16x8 hf[4];
        #pragma unroll
        for (int tt = 0; tt < 2; tt++) {
            f32x16 acc = __builtin_amdgcn_mfma_f32_32x32x16_bf16(rW1[tt], yb, Z, 0, 0, 0);
            #pragma unroll
            for (int z = 0; z < 16; z++) acc[z] = fmaxf(acc[z], 0.f);
            hf[2 * tt]     = pk8(acc, 0);
            hf[2 * tt + 1] = pk8(acc, 1);
        }

        // ---- P3: U = H @ W2  (K=64) -> C lane=l, rows=i
        f32x16 accU = __builtin_amdgcn_mfma_f32_32x32x16_bf16(hf[0], rW2[0], Z, 0, 0, 0);
        #pragma unroll
        for (int s = 1; s < 4; s++)
            accU = __builtin_amdgcn_mfma_f32_32x32x16_bf16(hf[s], rW2[s], accU, 0, 0, 0);
        bf16x8 uf[2] = { pk8(accU, 0), pk8(accU, 1) };

        // ---- P4: V = App @ U -> lane=i', rows=l
        f32x16 accV = __builtin_amdgcn_mfma_f32_32x32x16_bf16(uf[0], rApp[0], Z, 0, 0, 0);
        accV = __builtin_amdgcn_mfma_f32_32x32x16_bf16(uf[1], rApp[1], accV, 0, 0, 0);
        bf16x8 vf[2] = { pk8(accV, 0), pk8(accV, 1) };

        // ---- P5: HD^T = relu(W3 @ V^T + bpp), bias pre-loaded as C-in
        bf16x8 hd[4];
        #pragma unroll
        for (int tt = 0; tt < 2; tt++) {
            f32x16 acc = __builtin_amdgcn_mfma_f32_32x32x16_bf16(rW3[tt * 2 + 0], vf[0], rB16[tt], 0, 0, 0);
            acc = __builtin_amdgcn_mfma_f32_32x32x16_bf16(rW3[tt * 2 + 1], vf[1], acc, 0, 0, 0);
            #pragma unroll
            for (int z = 0; z < 16; z++) acc[z] = fmaxf(acc[z], 0.f);
            hd[2 * tt]     = pk8(acc, 0);
            hd[2 * tt + 1] = pk8(acc, 1);
        }

        // ---- P6: P = HD @ W4  (K=64) -> C lane=c, rows=i'
        f32x16 accP = __builtin_amdgcn_mfma_f32_32x32x16_bf16(hd[0], rW4[0], Z, 0, 0, 0);
        #pragma unroll
        for (int s = 1; s < 4; s++)
            accP = __builtin_amdgcn_mfma_f32_32x32x16_bf16(hd[s], rW4[s], accP, 0, 0, 0);
        bf16x8 pf[2] = { pk8(accP, 0), pk8(accP, 1) };

        // ---- P7 (SWAPPED): out^T = P^T @ A4s^T -> C col=lane=i'', rows=c
        //      pf as A (m=lane=c, k-slot->i' ladder); rA4b as B (n=lane=i'',
        //      same k-slot->i' mapping; identical table serves both roles).
        //      Valid output: half0 lanes 0..24, regs 0..2 = c.
        f32x16 accO = __builtin_amdgcn_mfma_f32_32x32x16_bf16(pf[0], rA4b[0], Z, 0, 0, 0);
        accO = __builtin_amdgcn_mfma_f32_32x32x16_bf16(pf[1], rA4b[1], accO, 0, 0, 0);
        if (do_store) {
            op[lane * 3 + 0] = accO[0] + b40;
            op[lane * 3 + 1] = accO[1] + b41;
            op[lane * 3 + 2] = accO[2] + b42;
        }
        op += NJC;
    }
}

// ---------------------------------------------------------------------------
extern "C" void kernel_launch(void* const* d_in, const int* in_sizes, int n_in,
                              void* d_out, int out_size, void* d_ws, size_t ws_size,
                              hipStream_t stream)
{
    const float* x  = (const float*)d_in[0];
    const float* A1 = (const float*)d_in[1];
    const float* W1 = (const float*)d_in[2];
    const float* b1 = (const float*)d_in[3];
    const float* A2 = (const float*)d_in[4];
    const float* W2 = (const float*)d_in[5];
    const float* b2 = (const float*)d_in[6];
    const float* A3 = (const float*)d_in[7];
    const float* W3 = (const float*)d_in[8];
    const float* b3 = (const float*)d_in[9];
    const float* A4 = (const float*)d_in[10];
    const float* W4 = (const float*)d_in[11];
    const float* b4 = (const float*)d_in[12];
    float* out = (float*)d_out;
    (void)d_ws; (void)ws_size;

    const int NT = in_sizes[0] / NJC;                 // 65536
    const int nblocks = NT / (NWAVE * NFPW);          // 1024

    gcn_fused<<<nblocks, NTHREADS, 0, stream>>>(
        x, A1, W1, b1, A2, W2, b2, A3, W3, b3, A4, W4, b4, out);
}